// Round 1
// baseline (389.560 us; speedup 1.0000x reference)
//
#include <hip/hip_runtime.h>
#include <math.h>

// TripletHard: B=8192, D=128, NUM_CLASSES=256, MARGIN=1.0, EPS=1e-5
// dist[i][j] = sqrt(max(sq_i + sq_j - 2*dot(f_i,f_j) + EPS, 0))
// pos[i] = 2nd-smallest same-class dist (diag included), neg[i] = min diff-class dist
// out = mean(max(MARGIN + pos - neg, 0))
//
// Monotonicity of sqrt/+EPS => track mins on d2 = sq_i + sq_j - 2*dot, sqrt at end.
//
// ws layout:
//   [0, 32768)           : sq, float[8192]
//   [32768, 32768+512KB) : partials, float4[4][8192] = (s1, s2, n1, pad) per j-split

#define BN 8192
#define MARGIN_F 1.0f
#define EPS_F 1e-5f

__global__ __launch_bounds__(256) void sq_kernel(const float* __restrict__ f,
                                                 float* __restrict__ sq) {
    int row = blockIdx.x * 256 + threadIdx.x;
    const float4* f4 = (const float4*)f + (size_t)row * 32;
    float4 s = make_float4(0.f, 0.f, 0.f, 0.f);
#pragma unroll
    for (int k = 0; k < 32; ++k) {
        float4 v = f4[k];
        s.x += v.x * v.x; s.y += v.y * v.y;
        s.z += v.z * v.z; s.w += v.w * v.w;
    }
    sq[row] = (s.x + s.y) + (s.z + s.w);
}

// Block: 256 threads = 16x16 (tx, ty). Block tile: 64 i-rows x 64 j-rows,
// 4x4 register tile per thread. Grid: (128 i-tiles, 4 j-splits).
// Each j-split covers 2048 j's = 32 tiles of 64.
__global__ __launch_bounds__(256) void main_kernel(const float* __restrict__ f,
                                                   const int* __restrict__ lbl,
                                                   const float* __restrict__ sq,
                                                   float4* __restrict__ part) {
    // rows padded to 132 floats (33 float4) -> 16B aligned, 2-way-max bank aliasing
    __shared__ __align__(16) float As[64 * 132];
    __shared__ __align__(16) float Bs[64 * 132];
    __shared__ float sqi[64], sqj[64];
    __shared__ int li[64], lj[64];

    const int t = threadIdx.x;
    const int i0 = blockIdx.x * 64;
    const int jpart = blockIdx.y;
    const int jbase = jpart * 2048;

    const float4* f4 = (const float4*)f;
    float4* As4 = (float4*)As;
    float4* Bs4 = (float4*)Bs;

    // Load A tile: 64 rows x 32 float4 = 2048 float4, 8 per thread, coalesced.
#pragma unroll
    for (int r = 0; r < 8; ++r) {
        int idx = t + r * 256;
        int row = idx >> 5, c = idx & 31;
        As4[row * 33 + c] = f4[(size_t)(i0 + row) * 32 + c];
    }
    if (t < 64) { sqi[t] = sq[i0 + t]; li[t] = lbl[i0 + t]; }

    const int tx = t & 15, ty = t >> 4;

    float s1[4], s2[4], n1[4];
#pragma unroll
    for (int p = 0; p < 4; ++p) { s1[p] = INFINITY; s2[p] = INFINITY; n1[p] = INFINITY; }

    for (int jt = 0; jt < 32; ++jt) {
        const int j0 = jbase + jt * 64;
        __syncthreads();  // previous tile's compute done before overwriting Bs
#pragma unroll
        for (int r = 0; r < 8; ++r) {
            int idx = t + r * 256;
            int row = idx >> 5, c = idx & 31;
            Bs4[row * 33 + c] = f4[(size_t)(j0 + row) * 32 + c];
        }
        if (t < 64) { sqj[t] = sq[j0 + t]; lj[t] = lbl[j0 + t]; }
        __syncthreads();

        float acc[4][4];
#pragma unroll
        for (int p = 0; p < 4; ++p)
#pragma unroll
            for (int q = 0; q < 4; ++q) acc[p][q] = 0.f;

#pragma unroll 8
        for (int k = 0; k < 32; ++k) {
            float4 a[4], b[4];
#pragma unroll
            for (int p = 0; p < 4; ++p) a[p] = As4[(ty + 16 * p) * 33 + k];
#pragma unroll
            for (int q = 0; q < 4; ++q) b[q] = Bs4[(tx + 16 * q) * 33 + k];
#pragma unroll
            for (int p = 0; p < 4; ++p)
#pragma unroll
                for (int q = 0; q < 4; ++q)
                    acc[p][q] += a[p].x * b[q].x + a[p].y * b[q].y +
                                 a[p].z * b[q].z + a[p].w * b[q].w;
        }

        // epilogue: fold 4x4 d2 values into running per-i-row state
#pragma unroll
        for (int p = 0; p < 4; ++p) {
            float si = sqi[ty + 16 * p];
            int cli = li[ty + 16 * p];
#pragma unroll
            for (int q = 0; q < 4; ++q) {
                float d2 = si + sqj[tx + 16 * q] - 2.0f * acc[p][q];
                if (cli == lj[tx + 16 * q]) {
                    // insert d2 into sorted pair (s1 <= s2)
                    float lo = fminf(s1[p], d2);
                    float hi = fminf(fmaxf(s1[p], d2), s2[p]);
                    s1[p] = lo; s2[p] = hi;
                } else {
                    n1[p] = fminf(n1[p], d2);
                }
            }
        }
    }

    // merge across the 16 tx-lanes sharing each i-row (butterfly, width 16)
#pragma unroll
    for (int m = 1; m < 16; m <<= 1) {
#pragma unroll
        for (int p = 0; p < 4; ++p) {
            float o1 = __shfl_xor(s1[p], m, 16);
            float o2 = __shfl_xor(s2[p], m, 16);
            float on = __shfl_xor(n1[p], m, 16);
            float lo = fminf(s1[p], o1);
            float hi = fminf(fmaxf(s1[p], o1), fminf(s2[p], o2));
            s1[p] = lo; s2[p] = hi;
            n1[p] = fminf(n1[p], on);
        }
    }

    if (tx == 0) {
#pragma unroll
        for (int p = 0; p < 4; ++p) {
            int row = i0 + ty + 16 * p;
            part[jpart * BN + row] = make_float4(s1[p], s2[p], n1[p], 0.f);
        }
    }
}

__device__ __forceinline__ void merge2(float& s1, float& s2, float o1, float o2) {
    float lo = fminf(s1, o1);
    float hi = fminf(fmaxf(s1, o1), fminf(s2, o2));
    s1 = lo; s2 = hi;
}

__global__ __launch_bounds__(512) void merge_kernel(const float4* __restrict__ part,
                                                    float* __restrict__ out) {
    int t = threadIdx.x;
    float sum = 0.f;
    for (int s = 0; s < 16; ++s) {
        int r = t + 512 * s;
        float4 a = part[r];
        float4 b = part[BN + r];
        float4 c = part[2 * BN + r];
        float4 d = part[3 * BN + r];
        float s1 = a.x, s2 = a.y, n = a.z;
        merge2(s1, s2, b.x, b.y); n = fminf(n, b.z);
        merge2(s1, s2, c.x, c.y); n = fminf(n, c.z);
        merge2(s1, s2, d.x, d.y); n = fminf(n, d.z);
        float pos = sqrtf(fmaxf(s2 + EPS_F, 0.f));
        float neg = sqrtf(fmaxf(n + EPS_F, 0.f));
        sum += fmaxf(MARGIN_F + pos - neg, 0.f);
    }
    // wave reduce (width 64) then cross-wave via LDS
    __shared__ float red[8];
#pragma unroll
    for (int m = 32; m >= 1; m >>= 1) sum += __shfl_down(sum, m, 64);
    if ((t & 63) == 0) red[t >> 6] = sum;
    __syncthreads();
    if (t == 0) {
        float tot = 0.f;
#pragma unroll
        for (int w = 0; w < 8; ++w) tot += red[w];
        out[0] = tot / (float)BN;
    }
}

extern "C" void kernel_launch(void* const* d_in, const int* in_sizes, int n_in,
                              void* d_out, int out_size, void* d_ws, size_t ws_size,
                              hipStream_t stream) {
    const float* f = (const float*)d_in[0];
    const int* lbl = (const int*)d_in[1];
    float* sq = (float*)d_ws;
    float4* part = (float4*)((char*)d_ws + 32768);
    float* out = (float*)d_out;

    sq_kernel<<<32, 256, 0, stream>>>(f, sq);
    main_kernel<<<dim3(128, 4), 256, 0, stream>>>(f, lbl, sq, part);
    merge_kernel<<<1, 512, 0, stream>>>(part, out);
}

// Round 2
// 128.907 us; speedup vs baseline: 3.0220x; 3.0220x over previous
//
#include <hip/hip_runtime.h>
#include <math.h>

// TripletHard B=8192 D=128 NC=256. MFMA bf16 Gram + streaming min-tracking.
// v[i][j] = sq_j - 2*dot(i,j) tracked (monotone shift by sq_i applied at end).
// ws: [0,32K) sq fp32[8192]; [32K, 32K+2M) F bf16[8192*128];
//     [32K+2M, +2M) partials float4[16][8192] (s1,s2,n1,0)

#define BN 8192
#define MARGIN_F 1.0f
#define EPS_F 1e-5f

typedef __attribute__((ext_vector_type(8))) short short8;
typedef __attribute__((ext_vector_type(4))) float floatx4;

__device__ __forceinline__ unsigned short bf16_rne(float x, float& r) {
    unsigned u = __float_as_uint(x);
    u += 0x7FFF + ((u >> 16) & 1);
    unsigned short h = (unsigned short)(u >> 16);
    r = __uint_as_float(((unsigned)h) << 16);
    return h;
}

// one row per thread: convert to bf16 (RNE) and sq from ROUNDED values
__global__ __launch_bounds__(256) void prep_kernel(const float* __restrict__ f,
                                                   unsigned short* __restrict__ fb,
                                                   float* __restrict__ sq) {
    int row = blockIdx.x * 256 + threadIdx.x;
    const float4* f4 = (const float4*)f + (size_t)row * 32;
    ushort4* o4 = (ushort4*)fb + (size_t)row * 32;
    float s = 0.f;
#pragma unroll
    for (int k = 0; k < 32; ++k) {
        float4 v = f4[k];
        float r0, r1, r2, r3;
        ushort4 o;
        o.x = bf16_rne(v.x, r0);
        o.y = bf16_rne(v.y, r1);
        o.z = bf16_rne(v.z, r2);
        o.w = bf16_rne(v.w, r3);
        o4[k] = o;
        s += r0 * r0 + r1 * r1 + r2 * r2 + r3 * r3;
    }
    sq[row] = s;
}

// Block: 256 thr = 4 waves (2x2), block tile 128x128, wave tile 64x64.
// A-frags in registers (whole K=128), B tile staged in LDS (pad 136 bf16/row).
// Grid: (64 i-tiles, 8 j-splits); each block scans 8 j-tiles of 128.
__global__ __launch_bounds__(256, 2) void main_kernel(const unsigned short* __restrict__ fb,
                                                      const int* __restrict__ lbl,
                                                      const float* __restrict__ sq,
                                                      float4* __restrict__ part) {
    __shared__ short Bs[128 * 136];  // 34816 B, stride 272B: b128 reads conflict-free
    __shared__ int lbl_sh[128];
    __shared__ float sqj_sh[128];

    const int t = threadIdx.x;
    const int lane = t & 63;
    const int wv = t >> 6;
    const int wm = wv >> 1, wn = wv & 1;
    const int q = lane >> 4, c = lane & 15;
    const int i0 = blockIdx.x * 128;
    const int jpart = blockIdx.y;

    const short8* F8 = (const short8*)fb;  // 16 chunks of 8 bf16 per row
    short8* Bs8 = (short8*)Bs;             // row stride 17 chunks

    // A-frags: A[m=c][k=q*8+j]; rows i0+wm*64+mf*16+c, chunk ks*4+q
    short8 a[4][4];
#pragma unroll
    for (int mf = 0; mf < 4; ++mf) {
        int row = i0 + wm * 64 + mf * 16 + c;
#pragma unroll
        for (int ks = 0; ks < 4; ++ks) a[mf][ks] = F8[row * 16 + ks * 4 + q];
    }

    // labels for the 16 i-rows this lane's accumulators cover (row = q*4+rg + mf*16)
    int li[4][4];
#pragma unroll
    for (int mf = 0; mf < 4; ++mf)
#pragma unroll
        for (int rg = 0; rg < 4; ++rg)
            li[mf][rg] = lbl[i0 + wm * 64 + mf * 16 + q * 4 + rg];

    float s1[4][4], s2[4][4], n1[4][4];
#pragma unroll
    for (int mf = 0; mf < 4; ++mf)
#pragma unroll
        for (int rg = 0; rg < 4; ++rg) {
            s1[mf][rg] = INFINITY; s2[mf][rg] = INFINITY; n1[mf][rg] = INFINITY;
        }

    for (int jt = 0; jt < 8; ++jt) {
        const int j0 = jpart * 1024 + jt * 128;
        __syncthreads();  // prior iter's Bs/lbl_sh/sqj_sh reads done
        // stage B tile: 128 rows x 16 chunks; contiguous 4KB per iteration
#pragma unroll
        for (int it = 0; it < 8; ++it) {
            int s = it * 256 + t;
            int r = s >> 4, cc = s & 15;
            Bs8[r * 17 + cc] = F8[(j0 + r) * 16 + cc];
        }
        if (t < 128) {
            lbl_sh[t] = lbl[j0 + t];
            sqj_sh[t] = sq[j0 + t];
        }
        __syncthreads();

        floatx4 acc[4][4];
#pragma unroll
        for (int mf = 0; mf < 4; ++mf)
#pragma unroll
            for (int nf = 0; nf < 4; ++nf) acc[mf][nf] = (floatx4)0.f;

#pragma unroll
        for (int ks = 0; ks < 4; ++ks) {
            short8 b[4];
#pragma unroll
            for (int nf = 0; nf < 4; ++nf) {
                int r = wn * 64 + nf * 16 + c;  // B[k][n]: n=c -> row j0+r
                b[nf] = Bs8[r * 17 + ks * 4 + q];
            }
#pragma unroll
            for (int mf = 0; mf < 4; ++mf)
#pragma unroll
                for (int nf = 0; nf < 4; ++nf)
                    acc[mf][nf] = __builtin_amdgcn_mfma_f32_16x16x32_bf16(
                        a[mf][ks], b[nf], acc[mf][nf], 0, 0, 0);
        }

        // epilogue: C/D map col=c, row=q*4+rg; fold v = sq_j - 2*dot
#pragma unroll
        for (int nf = 0; nf < 4; ++nf) {
            int jc = wn * 64 + nf * 16 + c;
            float sjc = sqj_sh[jc];
            int ljc = lbl_sh[jc];
#pragma unroll
            for (int mf = 0; mf < 4; ++mf)
#pragma unroll
                for (int rg = 0; rg < 4; ++rg) {
                    float v = fmaf(-2.0f, acc[mf][nf][rg], sjc);
                    bool same = (li[mf][rg] == ljc);
                    float vs = same ? v : INFINITY;
                    float vd = same ? INFINITY : v;
                    s2[mf][rg] = fminf(s2[mf][rg], fmaxf(s1[mf][rg], vs));
                    s1[mf][rg] = fminf(s1[mf][rg], vs);
                    n1[mf][rg] = fminf(n1[mf][rg], vd);
                }
        }
    }

    // merge across the 16 column-lanes (c) sharing each accumulator row
#pragma unroll
    for (int m = 1; m < 16; m <<= 1) {
#pragma unroll
        for (int mf = 0; mf < 4; ++mf)
#pragma unroll
            for (int rg = 0; rg < 4; ++rg) {
                float o1 = __shfl_xor(s1[mf][rg], m, 16);
                float o2 = __shfl_xor(s2[mf][rg], m, 16);
                float on = __shfl_xor(n1[mf][rg], m, 16);
                float lo = fminf(s1[mf][rg], o1);
                float hi = fminf(fmaxf(s1[mf][rg], o1), fminf(s2[mf][rg], o2));
                s1[mf][rg] = lo; s2[mf][rg] = hi;
                n1[mf][rg] = fminf(n1[mf][rg], on);
            }
    }

    if (c == 0) {
        int slice = jpart * 2 + wn;
#pragma unroll
        for (int mf = 0; mf < 4; ++mf)
#pragma unroll
            for (int rg = 0; rg < 4; ++rg) {
                int grow = i0 + wm * 64 + mf * 16 + q * 4 + rg;
                part[slice * BN + grow] =
                    make_float4(s1[mf][rg], s2[mf][rg], n1[mf][rg], 0.f);
            }
    }
}

__global__ __launch_bounds__(512) void merge_kernel(const float4* __restrict__ part,
                                                    const float* __restrict__ sq,
                                                    float* __restrict__ out) {
    int t = threadIdx.x;
    float sum = 0.f;
    for (int s = 0; s < 16; ++s) {
        int r = t + 512 * s;
        float s1 = INFINITY, s2v = INFINITY, n = INFINITY;
#pragma unroll
        for (int k = 0; k < 16; ++k) {
            float4 pp = part[k * BN + r];
            float lo = fminf(s1, pp.x);
            float hi = fminf(fmaxf(s1, pp.x), fminf(s2v, pp.y));
            s1 = lo; s2v = hi;
            n = fminf(n, pp.z);
        }
        float si = sq[r];
        float pos = sqrtf(fmaxf(si + s2v + EPS_F, 0.f));
        float neg = sqrtf(fmaxf(si + n + EPS_F, 0.f));
        sum += fmaxf(MARGIN_F + pos - neg, 0.f);
    }
    __shared__ float red[8];
#pragma unroll
    for (int m = 32; m >= 1; m >>= 1) sum += __shfl_down(sum, m, 64);
    if ((t & 63) == 0) red[t >> 6] = sum;
    __syncthreads();
    if (t == 0) {
        float tot = 0.f;
#pragma unroll
        for (int w = 0; w < 8; ++w) tot += red[w];
        out[0] = tot / (float)BN;
    }
}

extern "C" void kernel_launch(void* const* d_in, const int* in_sizes, int n_in,
                              void* d_out, int out_size, void* d_ws, size_t ws_size,
                              hipStream_t stream) {
    const float* f = (const float*)d_in[0];
    const int* lbl = (const int*)d_in[1];
    float* sq = (float*)d_ws;
    unsigned short* fb = (unsigned short*)((char*)d_ws + 32768);
    float4* part = (float4*)((char*)d_ws + 32768 + 2097152);
    float* out = (float*)d_out;

    prep_kernel<<<32, 256, 0, stream>>>(f, fb, sq);
    main_kernel<<<dim3(64, 8), 256, 0, stream>>>(fb, lbl, sq, part);
    merge_kernel<<<1, 512, 0, stream>>>(part, sq, out);
}

// Round 3
// 96.896 us; speedup vs baseline: 4.0204x; 1.3304x over previous
//
#include <hip/hip_runtime.h>
#include <math.h>

// TripletHard B=8192 D=128 NC=256. MFMA bf16 Gram + streaming min-tracking.
// v[i][j] = sq_j - 2*dot(i,j) tracked (monotone shift by sq_i applied at end).
// ws: [0,32K) sq fp32[8192]; [32K,32K+2M) F bf16[8192*128];
//     [32K+2M, +1M) partials float4[8][8192]; then bsum float[64]

#define BN 8192
#define MARGIN_F 1.0f
#define EPS_F 1e-5f

typedef __attribute__((ext_vector_type(8))) short short8;
typedef __attribute__((ext_vector_type(4))) float floatx4;

__device__ __forceinline__ unsigned short bf16_rne(float x, float& r) {
    unsigned u = __float_as_uint(x);
    u += 0x7FFF + ((u >> 16) & 1);
    unsigned short h = (unsigned short)(u >> 16);
    r = __uint_as_float(((unsigned)h) << 16);
    return h;
}

// 4 threads per row: convert to bf16 (RNE), sq from ROUNDED values
__global__ __launch_bounds__(256) void prep_kernel(const float* __restrict__ f,
                                                   unsigned short* __restrict__ fb,
                                                   float* __restrict__ sq) {
    int gid = blockIdx.x * 256 + threadIdx.x;  // 0..32767
    int row = gid >> 2, part = gid & 3;
    const float4* f4 = (const float4*)f + (size_t)row * 32 + part * 8;
    ushort4* o4 = (ushort4*)fb + (size_t)row * 32 + part * 8;
    float s = 0.f;
#pragma unroll
    for (int k = 0; k < 8; ++k) {
        float4 v = f4[k];
        float r0, r1, r2, r3;
        ushort4 o;
        o.x = bf16_rne(v.x, r0);
        o.y = bf16_rne(v.y, r1);
        o.z = bf16_rne(v.z, r2);
        o.w = bf16_rne(v.w, r3);
        o4[k] = o;
        s += r0 * r0 + r1 * r1 + r2 * r2 + r3 * r3;
    }
    s += __shfl_xor(s, 1, 4);
    s += __shfl_xor(s, 2, 4);
    if (part == 0) sq[row] = s;
}

// Block: 512 thr = 8 waves (4x2), block tile 128x128, wave tile 32x64
// (mf=2, nf=4). A and B tiles both streamed from LDS (pad 17 chunks/row).
// Register budget ~110 -> __launch_bounds__(512,4): 4 waves/SIMD, 16 waves/CU.
// Grid: (64 i-tiles, 8 j-splits); each block scans 8 j-tiles of 128.
__global__ __launch_bounds__(512, 4) void main_kernel(const unsigned short* __restrict__ fb,
                                                      const int* __restrict__ lbl,
                                                      const float* __restrict__ sq,
                                                      float4* __restrict__ part) {
    __shared__ short As[128 * 136];
    __shared__ short Bs[128 * 136];
    __shared__ int lbl_sh[128];
    __shared__ float sqj_sh[128];
    __shared__ float4 mrg[128];

    const int t = threadIdx.x;
    const int lane = t & 63;
    const int wv = t >> 6;       // 0..7
    const int wm = wv >> 1;      // 0..3 : 32-row strip
    const int wn = wv & 1;       // 0..1 : 64-col strip
    const int q = lane >> 4, c = lane & 15;
    const int i0 = blockIdx.x * 128;
    const int jpart = blockIdx.y;

    const short8* F8 = (const short8*)fb;  // 16 chunks of 8 bf16 per row
    short8* As8 = (short8*)As;             // row stride 17 chunks
    short8* Bs8 = (short8*)Bs;

    // stage A tile once: 128 rows x 16 chunks = 2048, 4 per thread
#pragma unroll
    for (int it = 0; it < 4; ++it) {
        int s = it * 512 + t;
        int r = s >> 4, cc = s & 15;
        As8[r * 17 + cc] = F8[(size_t)(i0 + r) * 16 + cc];
    }

    int li[2][4];
#pragma unroll
    for (int mf = 0; mf < 2; ++mf)
#pragma unroll
        for (int rg = 0; rg < 4; ++rg)
            li[mf][rg] = lbl[i0 + wm * 32 + mf * 16 + q * 4 + rg];

    float s1[2][4], s2[2][4], n1[2][4];
#pragma unroll
    for (int mf = 0; mf < 2; ++mf)
#pragma unroll
        for (int rg = 0; rg < 4; ++rg) {
            s1[mf][rg] = INFINITY; s2[mf][rg] = INFINITY; n1[mf][rg] = INFINITY;
        }

    for (int jt = 0; jt < 8; ++jt) {
        const int j0 = jpart * 1024 + jt * 128;
        __syncthreads();  // prior iter's Bs/lbl_sh/sqj_sh reads done (also covers As 1st iter)
#pragma unroll
        for (int it = 0; it < 4; ++it) {
            int s = it * 512 + t;
            int r = s >> 4, cc = s & 15;
            Bs8[r * 17 + cc] = F8[(size_t)(j0 + r) * 16 + cc];
        }
        if (t < 128) {
            lbl_sh[t] = lbl[j0 + t];
            sqj_sh[t] = sq[j0 + t];
        }
        __syncthreads();

        floatx4 acc[2][4];
#pragma unroll
        for (int mf = 0; mf < 2; ++mf)
#pragma unroll
            for (int nf = 0; nf < 4; ++nf) acc[mf][nf] = (floatx4)0.f;

#pragma unroll
        for (int ks = 0; ks < 4; ++ks) {
            short8 a[2], b[4];
#pragma unroll
            for (int mf = 0; mf < 2; ++mf)
                a[mf] = As8[(wm * 32 + mf * 16 + c) * 17 + ks * 4 + q];
#pragma unroll
            for (int nf = 0; nf < 4; ++nf)
                b[nf] = Bs8[(wn * 64 + nf * 16 + c) * 17 + ks * 4 + q];
#pragma unroll
            for (int mf = 0; mf < 2; ++mf)
#pragma unroll
                for (int nf = 0; nf < 4; ++nf)
                    acc[mf][nf] = __builtin_amdgcn_mfma_f32_16x16x32_bf16(
                        a[mf], b[nf], acc[mf][nf], 0, 0, 0);
        }

        // epilogue: C/D map col=c, row=q*4+rg; fold v = sq_j - 2*dot
#pragma unroll
        for (int nf = 0; nf < 4; ++nf) {
            int jc = wn * 64 + nf * 16 + c;
            float sjc = sqj_sh[jc];
            int ljc = lbl_sh[jc];
#pragma unroll
            for (int mf = 0; mf < 2; ++mf)
#pragma unroll
                for (int rg = 0; rg < 4; ++rg) {
                    float v = fmaf(-2.0f, acc[mf][nf][rg], sjc);
                    bool same = (li[mf][rg] == ljc);
                    float vs = same ? v : INFINITY;
                    float vd = same ? INFINITY : v;
                    s2[mf][rg] = fminf(s2[mf][rg], fmaxf(s1[mf][rg], vs));
                    s1[mf][rg] = fminf(s1[mf][rg], vs);
                    n1[mf][rg] = fminf(n1[mf][rg], vd);
                }
        }
    }

    // merge across the 16 column-lanes (c) sharing each accumulator row
#pragma unroll
    for (int m = 1; m < 16; m <<= 1) {
#pragma unroll
        for (int mf = 0; mf < 2; ++mf)
#pragma unroll
            for (int rg = 0; rg < 4; ++rg) {
                float o1 = __shfl_xor(s1[mf][rg], m, 16);
                float o2 = __shfl_xor(s2[mf][rg], m, 16);
                float on = __shfl_xor(n1[mf][rg], m, 16);
                float lo = fminf(s1[mf][rg], o1);
                float hi = fminf(fmaxf(s1[mf][rg], o1), fminf(s2[mf][rg], o2));
                s1[mf][rg] = lo; s2[mf][rg] = hi;
                n1[mf][rg] = fminf(n1[mf][rg], on);
            }
    }

    // in-block merge of the wn pair via LDS, then one slice write per jpart
    if (c == 0 && wn == 1) {
#pragma unroll
        for (int mf = 0; mf < 2; ++mf)
#pragma unroll
            for (int rg = 0; rg < 4; ++rg) {
                int row = wm * 32 + mf * 16 + q * 4 + rg;
                mrg[row] = make_float4(s1[mf][rg], s2[mf][rg], n1[mf][rg], 0.f);
            }
    }
    __syncthreads();
    if (c == 0 && wn == 0) {
#pragma unroll
        for (int mf = 0; mf < 2; ++mf)
#pragma unroll
            for (int rg = 0; rg < 4; ++rg) {
                int row = wm * 32 + mf * 16 + q * 4 + rg;
                float4 o = mrg[row];
                float a1 = s1[mf][rg], a2 = s2[mf][rg];
                float lo = fminf(a1, o.x);
                float hi = fminf(fmaxf(a1, o.x), fminf(a2, o.y));
                float nn = fminf(n1[mf][rg], o.z);
                part[jpart * BN + i0 + row] = make_float4(lo, hi, nn, 0.f);
            }
    }
}

__global__ __launch_bounds__(128) void mergeA_kernel(const float4* __restrict__ part,
                                                     const float* __restrict__ sq,
                                                     float* __restrict__ bsum) {
    int r = blockIdx.x * 128 + threadIdx.x;
    float s1 = INFINITY, s2v = INFINITY, n = INFINITY;
#pragma unroll
    for (int k = 0; k < 8; ++k) {
        float4 pp = part[k * BN + r];
        float lo = fminf(s1, pp.x);
        float hi = fminf(fmaxf(s1, pp.x), fminf(s2v, pp.y));
        s1 = lo; s2v = hi;
        n = fminf(n, pp.z);
    }
    float si = sq[r];
    float pos = sqrtf(fmaxf(si + s2v + EPS_F, 0.f));
    float neg = sqrtf(fmaxf(si + n + EPS_F, 0.f));
    float h = fmaxf(MARGIN_F + pos - neg, 0.f);
    __shared__ float red[2];
#pragma unroll
    for (int m = 32; m >= 1; m >>= 1) h += __shfl_down(h, m, 64);
    if ((threadIdx.x & 63) == 0) red[threadIdx.x >> 6] = h;
    __syncthreads();
    if (threadIdx.x == 0) bsum[blockIdx.x] = red[0] + red[1];
}

__global__ __launch_bounds__(64) void mergeB_kernel(const float* __restrict__ bsum,
                                                    float* __restrict__ out) {
    int t = threadIdx.x;
    float v = bsum[t];
#pragma unroll
    for (int m = 32; m >= 1; m >>= 1) v += __shfl_down(v, m, 64);
    if (t == 0) out[0] = v / (float)BN;
}

extern "C" void kernel_launch(void* const* d_in, const int* in_sizes, int n_in,
                              void* d_out, int out_size, void* d_ws, size_t ws_size,
                              hipStream_t stream) {
    const float* f = (const float*)d_in[0];
    const int* lbl = (const int*)d_in[1];
    float* sq = (float*)d_ws;
    unsigned short* fb = (unsigned short*)((char*)d_ws + 32768);
    float4* part = (float4*)((char*)d_ws + 32768 + 2097152);
    float* bsum = (float*)((char*)d_ws + 32768 + 2097152 + 8 * BN * 16);
    float* out = (float*)d_out;

    prep_kernel<<<128, 256, 0, stream>>>(f, fb, sq);
    main_kernel<<<dim3(64, 8), 512, 0, stream>>>(fb, lbl, sq, part);
    mergeA_kernel<<<64, 128, 0, stream>>>(part, sq, bsum);
    mergeB_kernel<<<1, 64, 0, stream>>>(bsum, out);
}